// Round 9
// baseline (200.355 us; speedup 1.0000x reference)
//
#include <hip/hip_runtime.h>
#include <hip/hip_bf16.h>
#include <stdint.h>

#define KDIM 4096
#define BM 128
#define BN 128
#define BK 32
#define KSPLIT 4
#define KQUAR (KDIM / KSPLIT)    // 1024
#define NT4 (KQUAR / BK)         // 32 K-steps per block

typedef __attribute__((ext_vector_type(8))) short bf16x8;
typedef __attribute__((ext_vector_type(4))) float f32x4;

__device__ inline unsigned short f2bf_bits(float f) {
  union { __hip_bfloat16 h; unsigned short u; } cv;
  cv.h = __float2bfloat16(f);
  return cv.u;
}

// Replicates: scaled = t / bm * 6; q = sign * nearest_palette(|scaled|) (ties -> lower);
// dq = q * (bm/6), rounded to bf16. Division kept exact (fp32 div) so palette
// boundary decisions bit-match the reference.
__device__ inline unsigned short qdq(float t, float bm, float scale) {
  float s = t / bm;
  s = s * 6.0f;
  float a = fabsf(s);
  float v;
  if (a <= 0.25f)      v = 0.0f;
  else if (a <= 0.75f) v = 0.5f;
  else if (a <= 1.25f) v = 1.0f;
  else if (a <= 1.75f) v = 1.5f;
  else if (a <= 2.5f)  v = 2.0f;
  else if (a <= 3.5f)  v = 3.0f;
  else if (a <= 5.0f)  v = 4.0f;
  else                 v = 6.0f;
  float q = copysignf(v, s);
  return f2bf_bits(q * scale);
}

// Fused quant+dequant for both tensors. One 8-lane subgroup = one 32-elem block.
__global__ void nvfp4_quant_dq2(const float* __restrict__ x, unsigned short* __restrict__ xq,
                                int nsub_x,
                                const float* __restrict__ w, unsigned short* __restrict__ wq,
                                int nsub_total) {
  int gid = blockIdx.x * blockDim.x + threadIdx.x;
  int sub = gid >> 3;
  if (sub >= nsub_total) return;
  const float* in;
  unsigned short* out;
  if (sub < nsub_x) { in = x; out = xq; }
  else { in = w; out = wq; sub -= nsub_x; }
  int l8 = gid & 7;
  long base = (long)sub * 32 + (long)l8 * 4;
  const float4 v = *(const float4*)(in + base);
  float amax = fmaxf(fmaxf(fabsf(v.x), fabsf(v.y)), fmaxf(fabsf(v.z), fabsf(v.w)));
  amax = fmaxf(amax, __shfl_xor(amax, 1));
  amax = fmaxf(amax, __shfl_xor(amax, 2));
  amax = fmaxf(amax, __shfl_xor(amax, 4));
  float bm = fmaxf(amax, 1e-12f);   // jnp.clip(max, 1e-12)
  float scale = bm / 6.0f;
  ushort4 o;
  o.x = qdq(v.x, bm, scale);
  o.y = qdq(v.y, bm, scale);
  o.z = qdq(v.z, bm, scale);
  o.w = qdq(v.w, bm, scale);
  *(ushort4*)(out + base) = o;
}

// C[M,N] += A[M,K](bf16) * B[N,K]^T(bf16), SPLIT-K=4 (C pre-zeroed; atomicAdd epi).
// R9: EXACT-FIT occupancy. 128x128 tile, BK=32 (m97's inner loop: 8 ds_read_b128 +
// 16 MFMA per wave-step, 64x64 wave tile), LDS dbuf 32 KB -> 4 blocks/CU = 128 KB
// exactly; grid = 256 tiles x 4 = 1024 = 4 x 256 CUs exactly (no ragged tail, the
// R8 failure); launch_bounds(256,4) caps VGPR at 128 -> 16 waves/CU.
// 4-chunk swizzle for BK=32: f(r) = (r + (r>>2)) & 3, applied inverse on the
// GLOBAL source + forward on ds_read -> 2-way bank aliasing (free, m136).
// Counted vmcnt(4) (never 0 in loop), raw barriers (R4-proven 2-barrier form).
// All 4 ks-blocks of a tile share an XCD -> panels + atomic C-tiles L2-local.
__global__ __launch_bounds__(256, 4) void gemm_bf16_bt(
    const unsigned short* __restrict__ A,  // [M, K]
    const unsigned short* __restrict__ B,  // [N, K]
    float* __restrict__ C, int M, int N) {
  __shared__ unsigned short As[2][BM * BK];   // 2 x 8 KB
  __shared__ unsigned short Bs[2][BN * BK];   // 2 x 8 KB   (32 KB total)

  const int tid = threadIdx.x;
  const int wave = tid >> 6;
  const int lane = tid & 63;
  const int wm = wave >> 1;       // 0..1  (64-row half)
  const int wn = wave & 1;        // 0..1  (64-col half)
  const int quad = lane >> 4;     // 0..3
  const int r16 = lane & 15;      // 0..15

  const int nbx = N / BN;
  const int nby = M / BM;
  int bx, by, ks;
  {
    int bid = blockIdx.x;
    if (nbx == 32 && nby == 8) {
      // XCD-chunked swizzle (1024 = 8 XCD x 128): XCD x owns bx in [4x,4x+4),
      // all by, ALL 4 ks -> B-panels, A-slices, and atomic C-tiles XCD-local.
      int xcd = bid & 7;
      int c = bid >> 3;            // 0..127
      ks = c & 3;
      int t = c >> 2;              // 0..31
      bx = xcd * 4 + (t & 3);
      by = t >> 2;                 // 0..7
    } else {
      ks = bid & (KSPLIT - 1);
      int tile = bid >> 2;
      bx = tile % nbx;
      by = tile / nbx;
    }
  }
  const int bm0 = by * BM;
  const int bn0 = bx * BN;
  const long k0 = (long)ks * KQUAR;

  // ---- staging map: tile = 128 rows x 4 chunks of 16B = 512 slots, 2/thread
  // each for A and B. LDS slot (row, ch) receives GLOBAL chunk ch ^ f(row),
  // f(row) = (row + (row>>2)) & 3  [inverse-swizzled source, linear LDS dest].
  const unsigned short* gA[2];
  const unsigned short* gB[2];
  int offS[2];
#pragma unroll
  for (int s = 0; s < 2; s++) {
    int slot = s * 256 + tid;        // 0..511
    int row = slot >> 2;             // 0..127
    int ch = slot & 3;               // 0..3
    int f = (row + (row >> 2)) & 3;
    int sch = ch ^ f;                // swizzled source chunk
    gA[s] = A + (long)(bm0 + row) * KDIM + k0 + sch * 8;
    gB[s] = B + (long)(bn0 + row) * KDIM + k0 + sch * 8;
    offS[s] = slot * 8;              // shorts; = row*32 + ch*8
  }

  // ---- fragment read offsets (shorts), 4-chunk swizzled: lane (quad,r16) wants
  // global chunk `quad` of its row -> LDS chunk = quad ^ f(row).
  int aoff[4], boff[4];
#pragma unroll
  for (int i = 0; i < 4; i++) {
    int ar = wm * 64 + i * 16 + r16;
    aoff[i] = ar * BK + ((quad ^ ((ar + (ar >> 2)) & 3)) * 8);
    int br = wn * 64 + i * 16 + r16;
    boff[i] = br * BK + ((quad ^ ((br + (br >> 2)) & 3)) * 8);
  }

  f32x4 acc[4][4] = {};

  unsigned short *sa0 = As[0], *sa1 = As[1];
  unsigned short *sb0 = Bs[0], *sb1 = Bs[1];

#define STAGE(SA, SB, T)                                                            \
  do {                                                                              \
    _Pragma("unroll") for (int s = 0; s < 2; s++) {                                 \
      __builtin_amdgcn_global_load_lds(                                             \
          (const __attribute__((address_space(1))) void*)(gA[s] + (long)(T) * BK),  \
          (__attribute__((address_space(3))) void*)((SA) + offS[s]), 16, 0, 0);     \
      __builtin_amdgcn_global_load_lds(                                             \
          (const __attribute__((address_space(1))) void*)(gB[s] + (long)(T) * BK),  \
          (__attribute__((address_space(3))) void*)((SB) + offS[s]), 16, 0, 0);     \
    }                                                                               \
  } while (0)

#define COMPUTE(SA, SB)                                                             \
  do {                                                                              \
    bf16x8 af[4], bfr[4];                                                           \
    _Pragma("unroll") for (int i = 0; i < 4; i++)                                   \
      af[i] = *(const bf16x8*)((SA) + aoff[i]);                                     \
    _Pragma("unroll") for (int j = 0; j < 4; j++)                                   \
      bfr[j] = *(const bf16x8*)((SB) + boff[j]);                                    \
    _Pragma("unroll") for (int i = 0; i < 4; i++)                                   \
      _Pragma("unroll") for (int j = 0; j < 4; j++)                                 \
        acc[i][j] =                                                                 \
            __builtin_amdgcn_mfma_f32_16x16x32_bf16(af[i], bfr[j], acc[i][j],       \
                                                    0, 0, 0);                       \
  } while (0)

  // prologue: 2 tiles in flight (8 outstanding global_load_lds per thread);
  // vmcnt(4) completes tile 0, leaves tile 1's 4 loads in flight.
  STAGE(sa0, sb0, 0);
  STAGE(sa1, sb1, 1);
  asm volatile("s_waitcnt vmcnt(4)" ::: "memory");
  __builtin_amdgcn_s_barrier();
  __builtin_amdgcn_sched_barrier(0);

#pragma unroll 1
  for (int t = 0; t < NT4; t++) {
    COMPUTE(sa0, sb0);
    if (t == NT4 - 1) break;
    // B1: all waves done reading buf cur -> safe to overwrite with tile t+2.
    asm volatile("s_waitcnt lgkmcnt(0)" ::: "memory");
    __builtin_amdgcn_s_barrier();
    __builtin_amdgcn_sched_barrier(0);
    if (t + 2 < NT4) {
      STAGE(sa0, sb0, t + 2);                          // 8 in flight again
      asm volatile("s_waitcnt vmcnt(4)" ::: "memory"); // tile t+1 landed
    } else {
      asm volatile("s_waitcnt vmcnt(0)" ::: "memory"); // last tile landed
    }
    // B2: tile t+1 visible to all waves.
    __builtin_amdgcn_s_barrier();
    __builtin_amdgcn_sched_barrier(0);
    unsigned short* tmp;
    tmp = sa0; sa0 = sa1; sa1 = tmp;
    tmp = sb0; sb0 = sb1; sb1 = tmp;
  }

#undef STAGE
#undef COMPUTE

  // Epilogue: split-K partial -> atomicAdd into pre-zeroed C.
  // C/D layout col = lane&15, row = quad*4 + reg. 16-lane col runs coalesce.
#pragma unroll
  for (int i = 0; i < 4; i++) {
#pragma unroll
    for (int j = 0; j < 4; j++) {
      const int row = bm0 + wm * 64 + i * 16 + quad * 4;
      const int col = bn0 + wn * 64 + j * 16 + r16;
#pragma unroll
      for (int r = 0; r < 4; r++)
        atomicAdd(&C[(long)(row + r) * N + col], acc[i][j][r]);
    }
  }
}

extern "C" void kernel_launch(void* const* d_in, const int* in_sizes, int n_in,
                              void* d_out, int out_size, void* d_ws, size_t ws_size,
                              hipStream_t stream) {
  const float* x = (const float*)d_in[0];   // [M, K] fp32
  const float* w = (const float*)d_in[1];   // [N, K] fp32
  float* out = (float*)d_out;               // [M, N] fp32

  const int MK = in_sizes[0];
  const int NK = in_sizes[1];
  const int M = MK / KDIM;
  const int N = NK / KDIM;

  unsigned short* xq = (unsigned short*)d_ws;        // [M, K] bf16
  unsigned short* wq = xq + (size_t)MK;              // [N, K] bf16

  // Split-K epilogue accumulates with atomicAdd -> zero C first (graph-safe).
  hipMemsetAsync(d_out, 0, out_size, stream);

  const int nsub_x = MK / 32;
  const int nsub_total = nsub_x + NK / 32;
  nvfp4_quant_dq2<<<dim3((nsub_total * 8 + 255) / 256), dim3(256), 0, stream>>>(
      x, xq, nsub_x, w, wq, nsub_total);

  dim3 grid((N / BN) * (M / BM) * KSPLIT);
  gemm_bf16_bt<<<grid, dim3(256), 0, stream>>>(xq, wq, out, M, N);
}

// Round 10
// 199.355 us; speedup vs baseline: 1.0050x; 1.0050x over previous
//
#include <hip/hip_runtime.h>
#include <hip/hip_bf16.h>
#include <stdint.h>

#define KDIM 4096
#define BM 256
#define BN 256
#define BK 64
#define KSPLIT 4
#define KQ (KDIM / KSPLIT)   // 1024
#define NT (KQ / BK)         // 16 K-tiles per block

typedef __attribute__((ext_vector_type(8))) short bf16x8;
typedef __attribute__((ext_vector_type(4))) float f32x4;

__device__ inline unsigned short f2bf_bits(float f) {
  union { __hip_bfloat16 h; unsigned short u; } cv;
  cv.h = __float2bfloat16(f);
  return cv.u;
}

// Replicates: scaled = t / bm * 6; q = sign * nearest_palette(|scaled|) (ties -> lower);
// dq = q * (bm/6), rounded to bf16. Division kept exact (fp32 div) so palette
// boundary decisions bit-match the reference.
__device__ inline unsigned short qdq(float t, float bm, float scale) {
  float s = t / bm;
  s = s * 6.0f;
  float a = fabsf(s);
  float v;
  if (a <= 0.25f)      v = 0.0f;
  else if (a <= 0.75f) v = 0.5f;
  else if (a <= 1.25f) v = 1.0f;
  else if (a <= 1.75f) v = 1.5f;
  else if (a <= 2.5f)  v = 2.0f;
  else if (a <= 3.5f)  v = 3.0f;
  else if (a <= 5.0f)  v = 4.0f;
  else                 v = 6.0f;
  float q = copysignf(v, s);
  return f2bf_bits(q * scale);
}

// Fused quant+dequant for both tensors. One 8-lane subgroup = one 32-elem block.
__global__ void nvfp4_quant_dq2(const float* __restrict__ x, unsigned short* __restrict__ xq,
                                int nsub_x,
                                const float* __restrict__ w, unsigned short* __restrict__ wq,
                                int nsub_total) {
  int gid = blockIdx.x * blockDim.x + threadIdx.x;
  int sub = gid >> 3;
  if (sub >= nsub_total) return;
  const float* in;
  unsigned short* out;
  if (sub < nsub_x) { in = x; out = xq; }
  else { in = w; out = wq; sub -= nsub_x; }
  int l8 = gid & 7;
  long base = (long)sub * 32 + (long)l8 * 4;
  const float4 v = *(const float4*)(in + base);
  float amax = fmaxf(fmaxf(fabsf(v.x), fabsf(v.y)), fmaxf(fabsf(v.z), fabsf(v.w)));
  amax = fmaxf(amax, __shfl_xor(amax, 1));
  amax = fmaxf(amax, __shfl_xor(amax, 2));
  amax = fmaxf(amax, __shfl_xor(amax, 4));
  float bm = fmaxf(amax, 1e-12f);   // jnp.clip(max, 1e-12)
  float scale = bm / 6.0f;
  ushort4 o;
  o.x = qdq(v.x, bm, scale);
  o.y = qdq(v.y, bm, scale);
  o.z = qdq(v.z, bm, scale);
  o.w = qdq(v.w, bm, scale);
  *(ushort4*)(out + base) = o;
}

// C[M,N] += A[M,K](bf16) * B[N,K]^T(bf16), SPLIT-K=4 (C pre-zeroed; atomicAdd epi).
// R10: 8-PHASE-STRUCTURE port (m201 template adapted). 256x256 tile, 512 threads,
// 8 waves (2Mx4N), WAVE TILE 128x64 (2.25x R4's FLOP/LDS-byte), BK=64, NT=16.
// Per K-tile, 4 phases: {read A-quadrant (4 b128) -> lgkm0 -> setprio(1) -> 16 MFMA
// -> setprio(0)}; B's 8 fragments read ONCE in ph0 and held in registers.
// Staging of tile t+1 front-loaded into phases 0-1 (A, then B) -> the boundary
// vmcnt(0) waits on loads issued >=2 compute phases (~500cyc) earlier.
// One barrier pair per K-tile (no intra-tile cross-wave hazards). LDS 128 KB dbuf,
// grid = 64 tiles x 4 ks = 256 blocks = 1 block/CU EXACT (R9 proved occupancy is
// not the lever; m201 ran this structure at 1 block/CU). Chunk-XOR swizzle on
// global source + ds_read addr (aligned 8-lane beats hit 8 distinct bank-groups).
__global__ __launch_bounds__(512, 2) void gemm_bf16_bt(
    const unsigned short* __restrict__ A,  // [M, K]
    const unsigned short* __restrict__ B,  // [N, K]
    float* __restrict__ C, int M, int N) {
  __shared__ unsigned short As[2][BM * BK];   // 2 x 32 KB
  __shared__ unsigned short Bs[2][BN * BK];   // 2 x 32 KB  (128 KB total)

  const int tid = threadIdx.x;    // 0..511
  const int wave = tid >> 6;      // 0..7
  const int lane = tid & 63;
  const int wm = wave >> 2;       // 0..1  (128-row half)
  const int wn = wave & 3;        // 0..3  (64-col quarter)
  const int quad = lane >> 4;     // 0..3
  const int r16 = lane & 15;      // 0..15

  const int nbx = N / BN;         // 16
  const int nby = M / BM;         // 4
  int bx, by, ks;
  {
    int bid = blockIdx.x;
    if (nbx == 16 && nby == 4) {
      // XCD-chunked (256 = 8 XCD x 32): XCD x owns bx in {2x,2x+1}, all by,
      // ALL 4 ks of each tile -> panels and atomic C-tiles XCD-local.
      int xcd = bid & 7;
      int c = bid >> 3;            // 0..31
      ks = c & 3;
      int tl = c >> 2;             // 0..7
      bx = xcd * 2 + (tl & 1);
      by = tl >> 1;                // 0..3
    } else {
      ks = bid & (KSPLIT - 1);
      int tile = bid >> 2;
      bx = tile % nbx;
      by = tile / nbx;
    }
  }
  const int bm0 = by * BM;
  const int bn0 = bx * BN;
  const long k0 = (long)ks * KQ;

  // ---- staging map: tile = 256 rows x 8 chunks of 16B = 2048 slots, 4/thread
  // each for A and B. LDS slot (row, ch) receives GLOBAL chunk (ch ^ (row&7))
  // [inverse-swizzled source, linear LDS dest -> swizzled ds_read conflict-free].
  const unsigned short* gA[4];
  const unsigned short* gB[4];
  int offS[4];
#pragma unroll
  for (int s = 0; s < 4; s++) {
    int slot = s * 512 + tid;        // 0..2047
    int row = slot >> 3;             // 0..255
    int ch = slot & 7;
    int sch = ch ^ (row & 7);
    gA[s] = A + (long)(bm0 + row) * KDIM + k0 + sch * 8;
    gB[s] = B + (long)(bn0 + row) * KDIM + k0 + sch * 8;
    offS[s] = slot * 8;              // shorts; = row*64 + ch*8
  }

  // ---- fragment addressing: row & 7 == r16 & 7 for all frag rows (row offsets
  // are multiples of 16) -> swizzle XOR term is q/i/j-independent.
  int xr[2];
  xr[0] = ((0 * 4 + quad) ^ (r16 & 7)) * 8;
  xr[1] = ((1 * 4 + quad) ^ (r16 & 7)) * 8;
  const int rowA = wm * 128 + r16;   // + q*32 + i*16
  const int rowB = wn * 64 + r16;    // + j*16

  f32x4 acc[8][4] = {};
  bf16x8 bfr[4][2];                  // B fragments, resident across the 4 phases

#define STAGE_A(SA, T)                                                              \
  do {                                                                              \
    _Pragma("unroll") for (int s = 0; s < 4; s++)                                   \
      __builtin_amdgcn_global_load_lds(                                             \
          (const __attribute__((address_space(1))) void*)(gA[s] + (long)(T) * BK),  \
          (__attribute__((address_space(3))) void*)((SA) + offS[s]), 16, 0, 0);     \
  } while (0)

#define STAGE_B(SB, T)                                                              \
  do {                                                                              \
    _Pragma("unroll") for (int s = 0; s < 4; s++)                                   \
      __builtin_amdgcn_global_load_lds(                                             \
          (const __attribute__((address_space(1))) void*)(gB[s] + (long)(T) * BK),  \
          (__attribute__((address_space(3))) void*)((SB) + offS[s]), 16, 0, 0);     \
  } while (0)

#define LOAD_B(CB)                                                                  \
  do {                                                                              \
    _Pragma("unroll") for (int j = 0; j < 4; j++)                                   \
      _Pragma("unroll") for (int kk = 0; kk < 2; kk++)                              \
        bfr[j][kk] = *(const bf16x8*)((CB) + (rowB + j * 16) * BK + xr[kk]);        \
  } while (0)

#define PHASE(Q, CA)                                                                \
  do {                                                                              \
    bf16x8 af[2][2];                                                                \
    _Pragma("unroll") for (int i = 0; i < 2; i++)                                   \
      _Pragma("unroll") for (int kk = 0; kk < 2; kk++)                              \
        af[i][kk] =                                                                 \
            *(const bf16x8*)((CA) + (rowA + (Q) * 32 + i * 16) * BK + xr[kk]);      \
    asm volatile("s_waitcnt lgkmcnt(0)" ::: "memory");                              \
    __builtin_amdgcn_sched_barrier(0);                                              \
    __builtin_amdgcn_s_setprio(1);                                                  \
    _Pragma("unroll") for (int kk = 0; kk < 2; kk++)                                \
      _Pragma("unroll") for (int i = 0; i < 2; i++)                                 \
        _Pragma("unroll") for (int j = 0; j < 4; j++)                               \
          acc[2 * (Q) + i][j] = __builtin_amdgcn_mfma_f32_16x16x32_bf16(            \
              af[i][kk], bfr[j][kk], acc[2 * (Q) + i][j], 0, 0, 0);                 \
    __builtin_amdgcn_s_setprio(0);                                                  \
  } while (0)

  unsigned short *cA = As[0], *nA = As[1];
  unsigned short *cB = Bs[0], *nB = Bs[1];

  // prologue: tile 0 staged (8 loads/thread)
  STAGE_A(cA, 0);
  STAGE_B(cB, 0);
  asm volatile("s_waitcnt vmcnt(0)" ::: "memory");
  __builtin_amdgcn_s_barrier();
  __builtin_amdgcn_sched_barrier(0);

#pragma unroll 1
  for (int t = 0; t < NT; t++) {
    // ph0: issue A(t+1) stage early; read all B-frags + A-quad0; MFMA q0
    if (t + 1 < NT) STAGE_A(nA, t + 1);
    LOAD_B(cB);
    PHASE(0, cA);
    // ph1: issue B(t+1) stage; MFMA q1
    if (t + 1 < NT) STAGE_B(nB, t + 1);
    PHASE(1, cA);
    // ph2, ph3: pure compute (stage loads in flight underneath)
    PHASE(2, cA);
    PHASE(3, cA);
    if (t == NT - 1) break;
    // boundary: all waves done reading cur bufs (their lgkm0s retired in-phase);
    // then wait tile t+1 (youngest load issued 2+ compute phases ago) + publish.
    __builtin_amdgcn_s_barrier();
    asm volatile("s_waitcnt vmcnt(0)" ::: "memory");
    __builtin_amdgcn_s_barrier();
    __builtin_amdgcn_sched_barrier(0);
    unsigned short* tp;
    tp = cA; cA = nA; nA = tp;
    tp = cB; cB = nB; nB = tp;
  }

#undef STAGE_A
#undef STAGE_B
#undef LOAD_B
#undef PHASE

  // Epilogue: split-K partial -> atomicAdd into pre-zeroed C.
  // C/D layout col = lane&15, row = quad*4 + reg. 16-lane col runs coalesce.
#pragma unroll
  for (int i = 0; i < 8; i++) {
#pragma unroll
    for (int j = 0; j < 4; j++) {
      const int row = bm0 + wm * 128 + i * 16 + quad * 4;
      const int col = bn0 + wn * 64 + j * 16 + r16;
#pragma unroll
      for (int r = 0; r < 4; r++)
        atomicAdd(&C[(long)(row + r) * N + col], acc[i][j][r]);
    }
  }
}

extern "C" void kernel_launch(void* const* d_in, const int* in_sizes, int n_in,
                              void* d_out, int out_size, void* d_ws, size_t ws_size,
                              hipStream_t stream) {
  const float* x = (const float*)d_in[0];   // [M, K] fp32
  const float* w = (const float*)d_in[1];   // [N, K] fp32
  float* out = (float*)d_out;               // [M, N] fp32

  const int MK = in_sizes[0];
  const int NK = in_sizes[1];
  const int M = MK / KDIM;
  const int N = NK / KDIM;

  unsigned short* xq = (unsigned short*)d_ws;        // [M, K] bf16
  unsigned short* wq = xq + (size_t)MK;              // [N, K] bf16

  // Split-K epilogue accumulates with atomicAdd -> zero C first (graph-safe).
  hipMemsetAsync(d_out, 0, out_size, stream);

  const int nsub_x = MK / 32;
  const int nsub_total = nsub_x + NK / 32;
  nvfp4_quant_dq2<<<dim3((nsub_total * 8 + 255) / 256), dim3(256), 0, stream>>>(
      x, xq, nsub_x, w, wq, nsub_total);

  dim3 grid((N / BN) * (M / BM) * KSPLIT);
  gemm_bf16_bt<<<grid, dim3(512), 0, stream>>>(xq, wq, out, M, N);
}

// Round 11
// 190.116 us; speedup vs baseline: 1.0539x; 1.0486x over previous
//
#include <hip/hip_runtime.h>
#include <hip/hip_bf16.h>
#include <stdint.h>

#define KDIM 4096
#define BM 128
#define BN 128
#define BK 32
#define KSPLIT 3
// BK-steps: 128 total, split 43/43/42; k0 = ks*43*32

typedef __attribute__((ext_vector_type(8))) short bf16x8;
typedef __attribute__((ext_vector_type(4))) float f32x4;

__device__ inline unsigned short f2bf_bits(float f) {
  union { __hip_bfloat16 h; unsigned short u; } cv;
  cv.h = __float2bfloat16(f);
  return cv.u;
}

// Replicates: scaled = t / bm * 6; q = sign * nearest_palette(|scaled|) (ties -> lower);
// dq = q * (bm/6), rounded to bf16. Division kept exact (fp32 div) so palette
// boundary decisions bit-match the reference.
__device__ inline unsigned short qdq(float t, float bm, float scale) {
  float s = t / bm;
  s = s * 6.0f;
  float a = fabsf(s);
  float v;
  if (a <= 0.25f)      v = 0.0f;
  else if (a <= 0.75f) v = 0.5f;
  else if (a <= 1.25f) v = 1.0f;
  else if (a <= 1.75f) v = 1.5f;
  else if (a <= 2.5f)  v = 2.0f;
  else if (a <= 3.5f)  v = 3.0f;
  else if (a <= 5.0f)  v = 4.0f;
  else                 v = 6.0f;
  float q = copysignf(v, s);
  return f2bf_bits(q * scale);
}

// Fused quant+dequant for both tensors. One 8-lane subgroup = one 32-elem block.
__global__ void nvfp4_quant_dq2(const float* __restrict__ x, unsigned short* __restrict__ xq,
                                int nsub_x,
                                const float* __restrict__ w, unsigned short* __restrict__ wq,
                                int nsub_total) {
  int gid = blockIdx.x * blockDim.x + threadIdx.x;
  int sub = gid >> 3;
  if (sub >= nsub_total) return;
  const float* in;
  unsigned short* out;
  if (sub < nsub_x) { in = x; out = xq; }
  else { in = w; out = wq; sub -= nsub_x; }
  int l8 = gid & 7;
  long base = (long)sub * 32 + (long)l8 * 4;
  const float4 v = *(const float4*)(in + base);
  float amax = fmaxf(fmaxf(fabsf(v.x), fabsf(v.y)), fmaxf(fabsf(v.z), fabsf(v.w)));
  amax = fmaxf(amax, __shfl_xor(amax, 1));
  amax = fmaxf(amax, __shfl_xor(amax, 2));
  amax = fmaxf(amax, __shfl_xor(amax, 4));
  float bm = fmaxf(amax, 1e-12f);   // jnp.clip(max, 1e-12)
  float scale = bm / 6.0f;
  ushort4 o;
  o.x = qdq(v.x, bm, scale);
  o.y = qdq(v.y, bm, scale);
  o.z = qdq(v.z, bm, scale);
  o.w = qdq(v.w, bm, scale);
  *(ushort4*)(out + base) = o;
}

// C[M,N] += A[M,K](bf16) * B[N,K]^T(bf16), SPLIT-K=3 (C pre-zeroed; atomicAdd epi).
// R11 = the m97 cell, exact-fit: 128x128 tile, BK=32, 4 waves (2x2), wave tile
// 64x64 -> per K-step 8 ds_read_b128 : 16 MFMA (m97's measured mix, 874-912 TF on
// this silicon at 12 waves/CU). LDS dbuf 32 KB -> 3 blocks/CU = 96 KB exactly;
// grid = 256 tiles x 3 = 768 = 3 x 256 CUs exactly (R8's raggedness eliminated);
// launch_bounds(256,3). Sync = R4/R9's validated counted-vmcnt two-barrier loop.
// BK=32 swizzle CORRECTED vs R9: f(row) = (row>>1)&3 -> within each 16-lane quad,
// (row-parity, chunk) covers all 8 bank-groups exactly 2x (2-way = free, m136).
// All 3 ks of a tile pinned to one XCD (panels + atomic C-tile L2-local).
__global__ __launch_bounds__(256, 3) void gemm_bf16_bt(
    const unsigned short* __restrict__ A,  // [M, K]
    const unsigned short* __restrict__ B,  // [N, K]
    float* __restrict__ C, int M, int N) {
  __shared__ unsigned short As[2][BM * BK];   // 2 x 8 KB
  __shared__ unsigned short Bs[2][BN * BK];   // 2 x 8 KB   (32 KB total)

  const int tid = threadIdx.x;
  const int wave = tid >> 6;
  const int lane = tid & 63;
  const int wm = wave >> 1;       // 0..1  (64-row half)
  const int wn = wave & 1;        // 0..1  (64-col half)
  const int quad = lane >> 4;     // 0..3
  const int r16 = lane & 15;      // 0..15

  const int nbx = N / BN;
  const int nby = M / BM;
  int bx, by, ks;
  {
    int bid = blockIdx.x;
    if (nbx == 32 && nby == 8) {
      // 768 = 8 XCD x 96: bid = (c<<3)|xcd; XCD x serves c = tile*3+ks for
      // tile 0..31 -> each XCD owns 32 tiles (bx in [4x,4x+4)) incl. all 3 ks.
      int xcd = bid & 7;
      int c = bid >> 3;            // 0..95
      int tile = c / 3;            // 0..31
      ks = c - tile * 3;
      bx = xcd * 4 + (tile & 3);
      by = tile >> 2;              // 0..7
    } else {
      ks = blockIdx.x % KSPLIT;
      int tile = blockIdx.x / KSPLIT;
      bx = tile % nbx;
      by = tile / nbx;
    }
  }
  const int bm0 = by * BM;
  const int bn0 = bx * BN;
  const long k0 = (long)ks * 1376;            // 43 BK-steps * 32
  const int NTk = (ks < 2) ? 43 : 42;         // 43+43+42 = 128 steps total

  // ---- staging map: tile = 128 rows x 4 chunks of 16B = 512 slots, 2/thread
  // each for A and B. LDS slot (row, ch) receives GLOBAL chunk ch ^ f(row),
  // f(row) = (row>>1)&3  [inverse-swizzled source, linear LDS dest].
  const unsigned short* gA[2];
  const unsigned short* gB[2];
  int offS[2];
#pragma unroll
  for (int s = 0; s < 2; s++) {
    int slot = s * 256 + tid;        // 0..511; wave-contiguous
    int row = slot >> 2;             // 0..127
    int ch = slot & 3;               // 0..3
    int sch = ch ^ ((row >> 1) & 3); // swizzled source chunk
    gA[s] = A + (long)(bm0 + row) * KDIM + k0 + sch * 8;
    gB[s] = B + (long)(bn0 + row) * KDIM + k0 + sch * 8;
    offS[s] = slot * 8;              // shorts; = row*32 + ch*8
  }

  // ---- fragment read offsets (shorts): lane (quad,r16) wants global chunk
  // `quad` of its row -> LDS chunk = quad ^ f(row). Row offsets are multiples
  // of 16 so f depends only on r16.
  int aoff[4], boff[4];
#pragma unroll
  for (int i = 0; i < 4; i++) {
    int ar = wm * 64 + i * 16 + r16;
    aoff[i] = ar * BK + ((quad ^ ((ar >> 1) & 3)) * 8);
    int br = wn * 64 + i * 16 + r16;
    boff[i] = br * BK + ((quad ^ ((br >> 1) & 3)) * 8);
  }

  f32x4 acc[4][4] = {};

  unsigned short *sa0 = As[0], *sa1 = As[1];
  unsigned short *sb0 = Bs[0], *sb1 = Bs[1];

#define STAGE(SA, SB, T)                                                            \
  do {                                                                              \
    _Pragma("unroll") for (int s = 0; s < 2; s++) {                                 \
      __builtin_amdgcn_global_load_lds(                                             \
          (const __attribute__((address_space(1))) void*)(gA[s] + (long)(T) * BK),  \
          (__attribute__((address_space(3))) void*)((SA) + offS[s]), 16, 0, 0);     \
      __builtin_amdgcn_global_load_lds(                                             \
          (const __attribute__((address_space(1))) void*)(gB[s] + (long)(T) * BK),  \
          (__attribute__((address_space(3))) void*)((SB) + offS[s]), 16, 0, 0);     \
    }                                                                               \
  } while (0)

#define COMPUTE(SA, SB)                                                             \
  do {                                                                              \
    bf16x8 af[4], bfr[4];                                                           \
    _Pragma("unroll") for (int i = 0; i < 4; i++)                                   \
      af[i] = *(const bf16x8*)((SA) + aoff[i]);                                     \
    _Pragma("unroll") for (int j = 0; j < 4; j++)                                   \
      bfr[j] = *(const bf16x8*)((SB) + boff[j]);                                    \
    _Pragma("unroll") for (int i = 0; i < 4; i++)                                   \
      _Pragma("unroll") for (int j = 0; j < 4; j++)                                 \
        acc[i][j] =                                                                 \
            __builtin_amdgcn_mfma_f32_16x16x32_bf16(af[i], bfr[j], acc[i][j],       \
                                                    0, 0, 0);                       \
  } while (0)

  // prologue: 2 tiles in flight (8 outstanding global_load_lds per thread);
  // vmcnt(4) completes tile 0, leaves tile 1's 4 loads in flight.
  STAGE(sa0, sb0, 0);
  STAGE(sa1, sb1, 1);
  asm volatile("s_waitcnt vmcnt(4)" ::: "memory");
  __builtin_amdgcn_s_barrier();
  __builtin_amdgcn_sched_barrier(0);

#pragma unroll 1
  for (int t = 0; t < NTk; t++) {
    COMPUTE(sa0, sb0);
    if (t == NTk - 1) break;
    // B1: all waves done reading buf cur -> safe to overwrite with tile t+2.
    asm volatile("s_waitcnt lgkmcnt(0)" ::: "memory");
    __builtin_amdgcn_s_barrier();
    __builtin_amdgcn_sched_barrier(0);
    if (t + 2 < NTk) {
      STAGE(sa0, sb0, t + 2);                          // 8 in flight again
      asm volatile("s_waitcnt vmcnt(4)" ::: "memory"); // tile t+1 landed
    } else {
      asm volatile("s_waitcnt vmcnt(0)" ::: "memory"); // last tile landed
    }
    // B2: tile t+1 visible to all waves.
    __builtin_amdgcn_s_barrier();
    __builtin_amdgcn_sched_barrier(0);
    unsigned short* tmp;
    tmp = sa0; sa0 = sa1; sa1 = tmp;
    tmp = sb0; sb0 = sb1; sb1 = tmp;
  }

#undef STAGE
#undef COMPUTE

  // Epilogue: split-K partial -> atomicAdd into pre-zeroed C.
  // C/D layout col = lane&15, row = quad*4 + reg. 16-lane col runs coalesce.
#pragma unroll
  for (int i = 0; i < 4; i++) {
#pragma unroll
    for (int j = 0; j < 4; j++) {
      const int row = bm0 + wm * 64 + i * 16 + quad * 4;
      const int col = bn0 + wn * 64 + j * 16 + r16;
#pragma unroll
      for (int r = 0; r < 4; r++)
        atomicAdd(&C[(long)(row + r) * N + col], acc[i][j][r]);
    }
  }
}

extern "C" void kernel_launch(void* const* d_in, const int* in_sizes, int n_in,
                              void* d_out, int out_size, void* d_ws, size_t ws_size,
                              hipStream_t stream) {
  const float* x = (const float*)d_in[0];   // [M, K] fp32
  const float* w = (const float*)d_in[1];   // [N, K] fp32
  float* out = (float*)d_out;               // [M, N] fp32

  const int MK = in_sizes[0];
  const int NK = in_sizes[1];
  const int M = MK / KDIM;
  const int N = NK / KDIM;

  unsigned short* xq = (unsigned short*)d_ws;        // [M, K] bf16
  unsigned short* wq = xq + (size_t)MK;              // [N, K] bf16

  // Split-K epilogue accumulates with atomicAdd -> zero C first (graph-safe).
  hipMemsetAsync(d_out, 0, out_size, stream);

  const int nsub_x = MK / 32;
  const int nsub_total = nsub_x + NK / 32;
  nvfp4_quant_dq2<<<dim3((nsub_total * 8 + 255) / 256), dim3(256), 0, stream>>>(
      x, xq, nsub_x, w, wq, nsub_total);

  dim3 grid((N / BN) * (M / BM) * KSPLIT);
  gemm_bf16_bt<<<grid, dim3(256), 0, stream>>>(xq, wq, out, M, N);
}

// Round 12
// 167.410 us; speedup vs baseline: 1.1968x; 1.1356x over previous
//
#include <hip/hip_runtime.h>
#include <hip/hip_bf16.h>
#include <stdint.h>

#define KDIM 4096
#define BM 64
#define BN 128
#define BK 64
#define NT (KDIM / BK)   // 64 K-steps

typedef __attribute__((ext_vector_type(8))) short bf16x8;
typedef __attribute__((ext_vector_type(4))) float f32x4;

__device__ inline unsigned short f2bf_bits(float f) {
  union { __hip_bfloat16 h; unsigned short u; } cv;
  cv.h = __float2bfloat16(f);
  return cv.u;
}

// Replicates: scaled = t / bm * 6; q = sign * nearest_palette(|scaled|) (ties -> lower);
// dq = q * (bm/6), rounded to bf16. Division kept exact (fp32 div) so palette
// boundary decisions bit-match the reference.
__device__ inline unsigned short qdq(float t, float bm, float scale) {
  float s = t / bm;
  s = s * 6.0f;
  float a = fabsf(s);
  float v;
  if (a <= 0.25f)      v = 0.0f;
  else if (a <= 0.75f) v = 0.5f;
  else if (a <= 1.25f) v = 1.0f;
  else if (a <= 1.75f) v = 1.5f;
  else if (a <= 2.5f)  v = 2.0f;
  else if (a <= 3.5f)  v = 3.0f;
  else if (a <= 5.0f)  v = 4.0f;
  else                 v = 6.0f;
  float q = copysignf(v, s);
  return f2bf_bits(q * scale);
}

// Fused quant+dequant for both tensors. One 8-lane subgroup = one 32-elem block.
__global__ void nvfp4_quant_dq2(const float* __restrict__ x, unsigned short* __restrict__ xq,
                                int nsub_x,
                                const float* __restrict__ w, unsigned short* __restrict__ wq,
                                int nsub_total) {
  int gid = blockIdx.x * blockDim.x + threadIdx.x;
  int sub = gid >> 3;
  if (sub >= nsub_total) return;
  const float* in;
  unsigned short* out;
  if (sub < nsub_x) { in = x; out = xq; }
  else { in = w; out = wq; sub -= nsub_x; }
  int l8 = gid & 7;
  long base = (long)sub * 32 + (long)l8 * 4;
  const float4 v = *(const float4*)(in + base);
  float amax = fmaxf(fmaxf(fabsf(v.x), fabsf(v.y)), fmaxf(fabsf(v.z), fabsf(v.w)));
  amax = fmaxf(amax, __shfl_xor(amax, 1));
  amax = fmaxf(amax, __shfl_xor(amax, 2));
  amax = fmaxf(amax, __shfl_xor(amax, 4));
  float bm = fmaxf(amax, 1e-12f);   // jnp.clip(max, 1e-12)
  float scale = bm / 6.0f;
  ushort4 o;
  o.x = qdq(v.x, bm, scale);
  o.y = qdq(v.y, bm, scale);
  o.z = qdq(v.z, bm, scale);
  o.w = qdq(v.w, bm, scale);
  *(ushort4*)(out + base) = o;
}

// C[M,N] = A[M,K](bf16) * B[N,K]^T(bf16).
// R12 = R4 revert (best measured: gemm 59us, total 166us). 64x128 tile, BK=64,
// 4 waves (2x2), each wave 32x64 via 2x4 grid of 16x16x32 MFMA. Grid = 16x32 =
// 512 blocks = 2 blocks/CU (the only lever that ever moved MfmaUtil). 48 KB LDS
// double buffer; counted s_waitcnt vmcnt(6) (never 0 in loop); raw s_barriers
// (no forced vmcnt(0) drain). Chunk-XOR swizzle on GLOBAL source + ds_read addr
// -> SQ_LDS_BANK_CONFLICT = 0 (R1-proven). Session evidence (R5-R11): BK=32,
// split-K atomics, depth-3, 4-phase, A-in-reg, 12-16 waves/CU all regress vs this.
__global__ __launch_bounds__(256, 2) void gemm_bf16_bt(
    const unsigned short* __restrict__ A,  // [M, K]
    const unsigned short* __restrict__ B,  // [N, K]
    float* __restrict__ C, int M, int N) {
  __shared__ unsigned short As[2][BM * BK];   // 2 x 8 KB
  __shared__ unsigned short Bs[2][BN * BK];   // 2 x 16 KB  (48 KB total)

  const int tid = threadIdx.x;
  const int wave = tid >> 6;
  const int lane = tid & 63;
  const int wm = wave >> 1;       // 0..1  (32-row half)
  const int wn = wave & 1;        // 0..1  (64-col half)
  const int quad = lane >> 4;     // 0..3
  const int r16 = lane & 15;      // 0..15

  const int nbx = N / BN;
  const int nby = M / BM;
  int bx, by;
  {
    int bid = blockIdx.x;
    if (nbx == 32 && nby == 16) {
      // XCD-chunked swizzle (512 = 8 XCD x 64, bijective): XCD x owns bx in
      // [4x, 4x+4) — its B-panels are XCD-private in L2 (read 16x, fetched once).
      // Consecutive c share by -> A-panel (512 KB) L2-resident while B streams.
      int xcd = bid & 7;
      int c = bid >> 3;            // 0..63
      bx = xcd * 4 + (c & 3);
      by = c >> 2;                 // 0..15
    } else {
      bx = bid % nbx;
      by = bid / nbx;
    }
  }
  const int bm0 = by * BM;
  const int bn0 = bx * BN;

  // ---- staging map: rows x 8 chunks of 16B. A: 512 slots (2/thread),
  // B: 1024 slots (4/thread). LDS slot (row, ch) receives GLOBAL chunk
  // (ch ^ (row&7)) [inverse-swizzled source, linear LDS dest].
  const unsigned short* gA[2];
  const unsigned short* gB[4];
  int offA[2], offB[4];
#pragma unroll
  for (int s = 0; s < 2; s++) {
    int slot = s * 256 + tid;        // 0..511
    int row = slot >> 3;             // 0..63
    int ch = slot & 7;
    int sch = ch ^ (row & 7);
    gA[s] = A + (long)(bm0 + row) * KDIM + sch * 8;
    offA[s] = slot * 8;
  }
#pragma unroll
  for (int s = 0; s < 4; s++) {
    int slot = s * 256 + tid;        // 0..1023
    int row = slot >> 3;             // 0..127
    int ch = slot & 7;
    int sch = ch ^ (row & 7);
    gB[s] = B + (long)(bn0 + row) * KDIM + sch * 8;
    offB[s] = slot * 8;
  }

  // ---- fragment read offsets (shorts), chunk-XOR swizzled
  int aoff[2][2], boff[2][4];
#pragma unroll
  for (int kk = 0; kk < 2; kk++) {
#pragma unroll
    for (int i = 0; i < 2; i++) {
      int ar = wm * 32 + i * 16 + r16;
      aoff[kk][i] = ar * BK + (((kk * 4 + quad) ^ (ar & 7)) * 8);
    }
#pragma unroll
    for (int j = 0; j < 4; j++) {
      int br = wn * 64 + j * 16 + r16;
      boff[kk][j] = br * BK + (((kk * 4 + quad) ^ (br & 7)) * 8);
    }
  }

  f32x4 acc[2][4] = {};

  unsigned short *sa0 = As[0], *sa1 = As[1];
  unsigned short *sb0 = Bs[0], *sb1 = Bs[1];

#define STAGE(SA, SB, T)                                                            \
  do {                                                                              \
    _Pragma("unroll") for (int s = 0; s < 2; s++)                                   \
      __builtin_amdgcn_global_load_lds(                                             \
          (const __attribute__((address_space(1))) void*)(gA[s] + (long)(T) * BK),  \
          (__attribute__((address_space(3))) void*)((SA) + offA[s]), 16, 0, 0);     \
    _Pragma("unroll") for (int s = 0; s < 4; s++)                                   \
      __builtin_amdgcn_global_load_lds(                                             \
          (const __attribute__((address_space(1))) void*)(gB[s] + (long)(T) * BK),  \
          (__attribute__((address_space(3))) void*)((SB) + offB[s]), 16, 0, 0);     \
  } while (0)

#define COMPUTE(SA, SB)                                                             \
  do {                                                                              \
    _Pragma("unroll") for (int kk = 0; kk < 2; kk++) {                              \
      bf16x8 af[2], bfr[4];                                                         \
      _Pragma("unroll") for (int i = 0; i < 2; i++)                                 \
        af[i] = *(const bf16x8*)((SA) + aoff[kk][i]);                               \
      _Pragma("unroll") for (int j = 0; j < 4; j++)                                 \
        bfr[j] = *(const bf16x8*)((SB) + boff[kk][j]);                              \
      _Pragma("unroll") for (int i = 0; i < 2; i++)                                 \
        _Pragma("unroll") for (int j = 0; j < 4; j++)                               \
          acc[i][j] =                                                               \
              __builtin_amdgcn_mfma_f32_16x16x32_bf16(af[i], bfr[j], acc[i][j],     \
                                                      0, 0, 0);                     \
    }                                                                               \
  } while (0)

  // prologue: 2 tiles in flight (12 outstanding global_load_lds per thread);
  // vmcnt(6) completes tile 0, leaves tile 1's 6 loads in flight.
  STAGE(sa0, sb0, 0);
  STAGE(sa1, sb1, 1);
  asm volatile("s_waitcnt vmcnt(6)" ::: "memory");
  __builtin_amdgcn_s_barrier();
  __builtin_amdgcn_sched_barrier(0);

#pragma unroll 1
  for (int t = 0; t < NT; t++) {
    COMPUTE(sa0, sb0);
    if (t == NT - 1) break;
    // B1: all waves done reading buf cur -> safe to overwrite with tile t+2.
    asm volatile("s_waitcnt lgkmcnt(0)" ::: "memory");
    __builtin_amdgcn_s_barrier();
    __builtin_amdgcn_sched_barrier(0);
    if (t + 2 < NT) {
      STAGE(sa0, sb0, t + 2);                          // 12 in flight again
      asm volatile("s_waitcnt vmcnt(6)" ::: "memory"); // tile t+1 landed
    } else {
      asm volatile("s_waitcnt vmcnt(0)" ::: "memory"); // last tile landed
    }
    // B2: tile t+1 visible to all waves.
    __builtin_amdgcn_s_barrier();
    __builtin_amdgcn_sched_barrier(0);
    unsigned short* tmp;
    tmp = sa0; sa0 = sa1; sa1 = tmp;
    tmp = sb0; sb0 = sb1; sb1 = tmp;
  }

#undef STAGE
#undef COMPUTE

  // Epilogue: C/D layout col = lane&15, row = quad*4 + reg
#pragma unroll
  for (int i = 0; i < 2; i++) {
#pragma unroll
    for (int j = 0; j < 4; j++) {
      const int row = bm0 + wm * 32 + i * 16 + quad * 4;
      const int col = bn0 + wn * 64 + j * 16 + r16;
#pragma unroll
      for (int r = 0; r < 4; r++)
        C[(long)(row + r) * N + col] = acc[i][j][r];
    }
  }
}

extern "C" void kernel_launch(void* const* d_in, const int* in_sizes, int n_in,
                              void* d_out, int out_size, void* d_ws, size_t ws_size,
                              hipStream_t stream) {
  const float* x = (const float*)d_in[0];   // [M, K] fp32
  const float* w = (const float*)d_in[1];   // [N, K] fp32
  float* out = (float*)d_out;               // [M, N] fp32

  const int MK = in_sizes[0];
  const int NK = in_sizes[1];
  const int M = MK / KDIM;
  const int N = NK / KDIM;

  unsigned short* xq = (unsigned short*)d_ws;        // [M, K] bf16
  unsigned short* wq = xq + (size_t)MK;              // [N, K] bf16

  const int nsub_x = MK / 32;
  const int nsub_total = nsub_x + NK / 32;
  nvfp4_quant_dq2<<<dim3((nsub_total * 8 + 255) / 256), dim3(256), 0, stream>>>(
      x, xq, nsub_x, w, wq, nsub_total);

  dim3 grid((N / BN) * (M / BM));
  gemm_bf16_bt<<<grid, dim3(256), 0, stream>>>(xq, wq, out, M, N);
}